// Round 8
// baseline (705.019 us; speedup 1.0000x reference)
//
#include <hip/hip_runtime.h>

// B=32 rows, N=8192, K=256. Straight-through estimator forward value
// == hard one-hot-sum + sample_memory (soft terms cancel numerically).
//
// R8: two dispatches (R7 showed intra-kernel cross-block sync costs 10x
// more than a dispatch boundary on CDNA4).
//  K1 (256 blocks, full chip): out=mem; counting-sort each 1024-elem
//     segment by DESCENDING top byte -> (key,col) pairs + 256-bin suffix
//     counts. Candidates for any threshold byte are a contiguous prefix.
//  K2 (32 blocks): sum 8 suffix arrays -> b0; gather ~350 prefix pairs;
//     brute-force exact top-K rank (key desc, col asc); scatter +1.0.

#define NROW 32
#define NCOL 8192
#define KSEL 256

__device__ __forceinline__ unsigned float_to_key(float f) {
    unsigned u = __float_as_uint(f);
    return (u & 0x80000000u) ? ~u : (u | 0x80000000u);  // monotone
}

// ---------------- K1 ----------------
__global__ __launch_bounds__(256) void k1_sort(
    const float* __restrict__ logits, const float* __restrict__ noise,
    const float* __restrict__ mem, float* __restrict__ out,
    uint2* __restrict__ pairs,      // [256 segments][1024]
    unsigned* __restrict__ suff)    // [256 segments][256] suffix counts
{
    __shared__ unsigned h[4][257];              // wave-private hist (+pad)
    __shared__ __align__(16) uint2 prs[1024];   // sorted pairs staging
    __shared__ unsigned wp[4];

    const int tid  = threadIdx.x;
    const int wave = tid >> 6;
    const int lane = tid & 63;
    const int base = blockIdx.x * 1024 + tid * 4;

    float4 lg = *(const float4*)(logits + base);
    float4 no = *(const float4*)(noise  + base);
    float4 mm = *(const float4*)(mem    + base);

    h[0][tid] = 0u; h[1][tid] = 0u; h[2][tid] = 0u; h[3][tid] = 0u;

    unsigned k[4];
    k[0] = float_to_key(lg.x + no.x + mm.x * -1000.0f);
    k[1] = float_to_key(lg.y + no.y + mm.y * -1000.0f);
    k[2] = float_to_key(lg.z + no.z + mm.z * -1000.0f);
    k[3] = float_to_key(lg.w + no.w + mm.w * -1000.0f);

    *(float4*)(out + base) = mm;                // prefill out = mem
    __syncthreads();                            // B1

    unsigned rnk[4];
#pragma unroll
    for (int i = 0; i < 4; ++i)
        rnk[i] = atomicAdd(&h[wave][k[i] >> 24], 1u);   // within-wave rank
    __syncthreads();                            // B2

    // thread t owns byte d = 255 - t: suffix counts + scatter offsets
    const int d = 255 - tid;
    unsigned c0 = h[0][d], c1 = h[1][d], c2 = h[2][d], c3 = h[3][d];
    unsigned c = c0 + c1 + c2 + c3;
    unsigned s = c;                             // inclusive scan over tid asc
#pragma unroll
    for (int off = 1; off < 64; off <<= 1) {
        unsigned nv = __shfl_up(s, off, 64);
        if (lane >= off) s += nv;
    }
    if (lane == 63) wp[wave] = s;
    __syncthreads();                            // B3
    {
        unsigned add = 0;
        for (int w = 0; w < wave; ++w) add += wp[w];
        const unsigned incl = s + add;          // count(bytes >= d)
        const unsigned dOff = incl - c;         // count(bytes >  d)
        suff[blockIdx.x * 256 + d] = incl;      // publish suffix count
        // overwrite h[w][d] with scatter base for (wave w, byte d)
        h[0][d] = dOff;
        h[1][d] = dOff + c0;
        h[2][d] = dOff + c0 + c1;
        h[3][d] = dOff + c0 + c1 + c2;
    }
    __syncthreads();                            // B4

    // scatter my 4 pairs into descending-byte order
#pragma unroll
    for (int i = 0; i < 4; ++i) {
        const unsigned pos = h[wave][k[i] >> 24] + rnk[i];
        prs[pos] = make_uint2(k[i], (unsigned)(tid * 4 + i));  // local col
    }
    __syncthreads();                            // B5

    // coalesced write: 1024 uint2 = 512 uint4
    uint4* gp = (uint4*)(pairs + (size_t)blockIdx.x * 1024);
    const uint4* lp = (const uint4*)prs;
    gp[tid]       = lp[tid];
    gp[tid + 256] = lp[tid + 256];
}

// ---------------- K2 ----------------
__global__ __launch_bounds__(256) void k2_select(
    const uint2* __restrict__ pairs, const unsigned* __restrict__ suff,
    float* __restrict__ out)
{
    __shared__ unsigned rs[256];
    __shared__ unsigned Ls[8];
    __shared__ unsigned shb0;
    __shared__ __align__(16) uint2 cand[8192];  // worst case; actual ~350

    const int tid = threadIdx.x;
    const int r   = blockIdx.x;

    // row suffix counts per byte
    unsigned v = 0;
#pragma unroll
    for (int sg = 0; sg < 8; ++sg) v += suff[(r * 8 + sg) * 256 + tid];
    rs[tid] = v;
    __syncthreads();                            // B1
    if (rs[tid] >= KSEL && (tid == 255 || rs[tid + 1] < KSEL)) shb0 = (unsigned)tid;
    __syncthreads();                            // B2
    const unsigned b0 = shb0;

    if (tid < 8) Ls[tid] = suff[(r * 8 + tid) * 256 + b0];
    __syncthreads();                            // B3

    unsigned off[9];
    off[0] = 0;
#pragma unroll
    for (int sg = 0; sg < 8; ++sg) off[sg + 1] = off[sg] + Ls[sg];
    const unsigned total = off[8];              // >= KSEL by choice of b0

    // gather candidate prefixes of each sorted segment
#pragma unroll
    for (int sg = 0; sg < 8; ++sg) {
        const uint2* pp = pairs + (size_t)(r * 8 + sg) * 1024;
        for (unsigned i = tid; i < Ls[sg]; i += 256) {
            uint2 e = pp[i];
            e.y += (unsigned)(sg * 1024);       // local col -> row col
            cand[off[sg] + i] = e;
        }
    }
    __syncthreads();                            // B4

    // exact top-K by brute-force rank: (key desc, col asc)
    for (unsigned i = tid; i < total; i += 256) {
        const unsigned ki = cand[i].x, ci = cand[i].y;
        unsigned cnt = 0;
        for (unsigned j = 0; j < total; ++j) {
            const unsigned kj = cand[j].x;
            cnt += (kj > ki || (kj == ki && cand[j].y < ci)) ? 1u : 0u;
        }
        if (cnt < KSEL) atomicAdd(out + r * NCOL + ci, 1.0f);
    }
}

// ---------------- Fallback: proven R5 single kernel (~64 us) ----------------
#define H0S 4097
__global__ __launch_bounds__(1024) void topk_single32(
    const float* __restrict__ logits, const float* __restrict__ noise,
    const float* __restrict__ mem, float* __restrict__ out)
{
    __shared__ unsigned hist0[4 * H0S];
    __shared__ __align__(16) unsigned hist1[4096];
    __shared__ unsigned hist2[256];
    __shared__ unsigned wpart[16];
    __shared__ unsigned sh_pn[2];

    const int tid  = threadIdx.x;
    const int wave = tid >> 6;
    const int lane = tid & 63;
    const int grp  = wave >> 2;
    const int base = blockIdx.x * NCOL + tid * 8;

    float4 lg0 = ((const float4*)(logits + base))[0];
    float4 lg1 = ((const float4*)(logits + base))[1];
    float4 no0 = ((const float4*)(noise  + base))[0];
    float4 no1 = ((const float4*)(noise  + base))[1];
    float4 mm0 = ((const float4*)(mem    + base))[0];
    float4 mm1 = ((const float4*)(mem    + base))[1];

    unsigned key[8];
    key[0] = float_to_key(lg0.x + no0.x + mm0.x * -1000.0f);
    key[1] = float_to_key(lg0.y + no0.y + mm0.y * -1000.0f);
    key[2] = float_to_key(lg0.z + no0.z + mm0.z * -1000.0f);
    key[3] = float_to_key(lg0.w + no0.w + mm0.w * -1000.0f);
    key[4] = float_to_key(lg1.x + no1.x + mm1.x * -1000.0f);
    key[5] = float_to_key(lg1.y + no1.y + mm1.y * -1000.0f);
    key[6] = float_to_key(lg1.z + no1.z + mm1.z * -1000.0f);
    key[7] = float_to_key(lg1.w + no1.w + mm1.w * -1000.0f);

    for (int i = tid; i < 4 * H0S; i += 1024) hist0[i] = 0u;
    for (int i = tid; i < 4096; i += 1024) hist1[i] = 0u;
    if (tid < 256) hist2[tid] = 0u;
    __syncthreads();

    {
        unsigned* h0 = hist0 + grp * H0S;
#pragma unroll
        for (int i = 0; i < 8; ++i) atomicAdd(&h0[key[i] >> 20], 1u);
    }
    __syncthreads();

    unsigned need = KSEL;
    unsigned p12, p24;
    const int dbase = 4095 - 4 * tid;
    {
        unsigned c[4], tot = 0;
#pragma unroll
        for (int j = 0; j < 4; ++j) {
            const int d = dbase - j;
            c[j] = hist0[d] + hist0[H0S + d] + hist0[2 * H0S + d] + hist0[3 * H0S + d];
            tot += c[j];
        }
        unsigned s = tot;
#pragma unroll
        for (int off = 1; off < 64; off <<= 1) {
            unsigned nv = __shfl_up(s, off, 64);
            if (lane >= off) s += nv;
        }
        if (lane == 63) wpart[wave] = s;
        __syncthreads();
        unsigned add = 0;
        for (int w = 0; w < wave; ++w) add += wpart[w];
        unsigned cum = s + add - tot;
#pragma unroll
        for (int j = 0; j < 4; ++j) {
            unsigned nc = cum + c[j];
            if (nc >= need && cum < need) { sh_pn[0] = (unsigned)(dbase - j); sh_pn[1] = need - cum; }
            cum = nc;
        }
    }
    __syncthreads();
    p12 = sh_pn[0]; need = sh_pn[1];

#pragma unroll
    for (int i = 0; i < 8; ++i)
        if ((key[i] >> 20) == p12)
            atomicAdd(&hist1[(key[i] >> 8) & 4095u], 1u);
    __syncthreads();
    {
        uint4 v = *(const uint4*)&hist1[dbase - 3];
        unsigned c[4] = {v.w, v.z, v.y, v.x};
        unsigned tot = c[0] + c[1] + c[2] + c[3];
        unsigned s = tot;
#pragma unroll
        for (int off = 1; off < 64; off <<= 1) {
            unsigned nv = __shfl_up(s, off, 64);
            if (lane >= off) s += nv;
        }
        if (lane == 63) wpart[wave] = s;
        __syncthreads();
        unsigned add = 0;
        for (int w = 0; w < wave; ++w) add += wpart[w];
        unsigned cum = s + add - tot;
#pragma unroll
        for (int j = 0; j < 4; ++j) {
            unsigned nc = cum + c[j];
            if (nc >= need && cum < need) { sh_pn[0] = (unsigned)(dbase - j); sh_pn[1] = need - cum; }
            cum = nc;
        }
    }
    __syncthreads();
    p24 = (p12 << 12) | sh_pn[0]; need = sh_pn[1];

#pragma unroll
    for (int i = 0; i < 8; ++i)
        if ((key[i] >> 8) == p24)
            atomicAdd(&hist2[key[i] & 255u], 1u);
    __syncthreads();

    if (wave == 0) {
        const int d0 = 255 - 4 * lane;
        unsigned c0 = hist2[d0], c1 = hist2[d0 - 1],
                 c2 = hist2[d0 - 2], c3 = hist2[d0 - 3];
        unsigned tot = c0 + c1 + c2 + c3, s = tot;
#pragma unroll
        for (int off = 1; off < 64; off <<= 1) {
            unsigned nv = __shfl_up(s, off, 64);
            if (lane >= off) s += nv;
        }
        unsigned P = s - tot;
        unsigned cum0 = P + c0, cum1 = cum0 + c1, cum2 = cum1 + c2, cum3 = cum2 + c3;
        if (cum0 >= need && P < need)         { sh_pn[0] = (unsigned)d0;       sh_pn[1] = need - P;    }
        else if (cum1 >= need && cum0 < need) { sh_pn[0] = (unsigned)(d0 - 1); sh_pn[1] = need - cum0; }
        else if (cum2 >= need && cum1 < need) { sh_pn[0] = (unsigned)(d0 - 2); sh_pn[1] = need - cum1; }
        else if (cum3 >= need && cum2 < need) { sh_pn[0] = (unsigned)(d0 - 3); sh_pn[1] = need - cum2; }
    }
    __syncthreads();
    const unsigned T     = (p24 << 8) | sh_pn[0];
    const unsigned needF = sh_pn[1];

    unsigned local_eq = 0;
#pragma unroll
    for (int i = 0; i < 8; ++i) local_eq += (key[i] == T) ? 1u : 0u;
    unsigned s2 = local_eq;
#pragma unroll
    for (int off = 1; off < 64; off <<= 1) {
        unsigned nv = __shfl_up(s2, off, 64);
        if (lane >= off) s2 += nv;
    }
    if (lane == 63) wpart[wave] = s2;
    __syncthreads();
    unsigned rank = s2 - local_eq;
    for (int w = 0; w < wave; ++w) rank += wpart[w];

    float o[8];
#pragma unroll
    for (int i = 0; i < 8; ++i) {
        float sel;
        if (key[i] > T)       sel = 1.0f;
        else if (key[i] == T) { sel = (rank < needF) ? 1.0f : 0.0f; ++rank; }
        else                  sel = 0.0f;
        o[i] = sel;
    }
    o[0] += mm0.x; o[1] += mm0.y; o[2] += mm0.z; o[3] += mm0.w;
    o[4] += mm1.x; o[5] += mm1.y; o[6] += mm1.z; o[7] += mm1.w;
    ((float4*)(out + base))[0] = make_float4(o[0], o[1], o[2], o[3]);
    ((float4*)(out + base))[1] = make_float4(o[4], o[5], o[6], o[7]);
}

extern "C" void kernel_launch(void* const* d_in, const int* in_sizes, int n_in,
                              void* d_out, int out_size, void* d_ws, size_t ws_size,
                              hipStream_t stream) {
    const float* logits = (const float*)d_in[0];
    const float* noise  = (const float*)d_in[1];
    const float* mem    = (const float*)d_in[2];
    float* out = (float*)d_out;

    const size_t pairs_bytes = (size_t)256 * 1024 * sizeof(uint2);   // 2 MB
    const size_t suff_bytes  = (size_t)256 * 256 * sizeof(unsigned); // 256 KB

    if (ws_size >= pairs_bytes + suff_bytes) {
        uint2*    pairs = (uint2*)d_ws;
        unsigned* suff  = (unsigned*)((char*)d_ws + pairs_bytes);
        k1_sort<<<256, 256, 0, stream>>>(logits, noise, mem, out, pairs, suff);
        k2_select<<<NROW, 256, 0, stream>>>(pairs, suff, out);
    } else {
        topk_single32<<<NROW, 1024, 0, stream>>>(logits, noise, mem, out);
    }
}

// Round 9
// 69.329 us; speedup vs baseline: 10.1691x; 10.1691x over previous
//
#include <hip/hip_runtime.h>

// B=32 rows, N=8192, K=256. Straight-through estimator forward value
// == hard one-hot-sum + sample_memory (soft terms cancel numerically).
//
// R9: K1 (256 blocks, full chip) = R8's counting sort by descending top
// byte (proven): out=mem, sorted (key,col) pairs + 256-bin suffix counts.
// K2 (32 blocks) replaces R8's O(total^2) brute-force rank (651 us!) with
// histogram refinement: byte>b0 selected outright; b0-class refined by
// two 12-bit LDS hist passes -> exact threshold + needF; ties (typically
// 1) ranked by column via a small list; ~256 scattered +1.0 adds/row.

#define NROW 32
#define NCOL 8192
#define KSEL 256

__device__ __forceinline__ unsigned float_to_key(float f) {
    unsigned u = __float_as_uint(f);
    return (u & 0x80000000u) ? ~u : (u | 0x80000000u);  // monotone
}

// ---------------- K1: counting sort by descending top byte ----------------
__global__ __launch_bounds__(256) void k1_sort(
    const float* __restrict__ logits, const float* __restrict__ noise,
    const float* __restrict__ mem, float* __restrict__ out,
    uint2* __restrict__ pairs,      // [256 segments][1024]
    unsigned* __restrict__ suff)    // [256 segments][256] suffix counts
{
    __shared__ unsigned h[4][257];              // wave-private hist (+pad)
    __shared__ __align__(16) uint2 prs[1024];   // sorted pairs staging
    __shared__ unsigned wp[4];

    const int tid  = threadIdx.x;
    const int wave = tid >> 6;
    const int lane = tid & 63;
    const int base = blockIdx.x * 1024 + tid * 4;

    float4 lg = *(const float4*)(logits + base);
    float4 no = *(const float4*)(noise  + base);
    float4 mm = *(const float4*)(mem    + base);

    h[0][tid] = 0u; h[1][tid] = 0u; h[2][tid] = 0u; h[3][tid] = 0u;

    unsigned k[4];
    k[0] = float_to_key(lg.x + no.x + mm.x * -1000.0f);
    k[1] = float_to_key(lg.y + no.y + mm.y * -1000.0f);
    k[2] = float_to_key(lg.z + no.z + mm.z * -1000.0f);
    k[3] = float_to_key(lg.w + no.w + mm.w * -1000.0f);

    *(float4*)(out + base) = mm;                // prefill out = mem
    __syncthreads();                            // B1

    unsigned rnk[4];
#pragma unroll
    for (int i = 0; i < 4; ++i)
        rnk[i] = atomicAdd(&h[wave][k[i] >> 24], 1u);   // within-wave rank
    __syncthreads();                            // B2

    // thread t owns byte d = 255 - t: suffix counts + scatter offsets
    const int d = 255 - tid;
    unsigned c0 = h[0][d], c1 = h[1][d], c2 = h[2][d], c3 = h[3][d];
    unsigned c = c0 + c1 + c2 + c3;
    unsigned s = c;                             // inclusive scan over tid asc
#pragma unroll
    for (int off = 1; off < 64; off <<= 1) {
        unsigned nv = __shfl_up(s, off, 64);
        if (lane >= off) s += nv;
    }
    if (lane == 63) wp[wave] = s;
    __syncthreads();                            // B3
    {
        unsigned add = 0;
        for (int w = 0; w < wave; ++w) add += wp[w];
        const unsigned incl = s + add;          // count(bytes >= d)
        const unsigned dOff = incl - c;         // count(bytes >  d)
        suff[blockIdx.x * 256 + d] = incl;      // publish suffix count
        h[0][d] = dOff;
        h[1][d] = dOff + c0;
        h[2][d] = dOff + c0 + c1;
        h[3][d] = dOff + c0 + c1 + c2;
    }
    __syncthreads();                            // B4

#pragma unroll
    for (int i = 0; i < 4; ++i) {
        const unsigned pos = h[wave][k[i] >> 24] + rnk[i];
        prs[pos] = make_uint2(k[i], (unsigned)(tid * 4 + i));  // local col
    }
    __syncthreads();                            // B5

    uint4* gp = (uint4*)(pairs + (size_t)blockIdx.x * 1024);
    const uint4* lp = (const uint4*)prs;
    gp[tid]       = lp[tid];
    gp[tid + 256] = lp[tid + 256];
}

// ---------------- K2: hist-refine select + scatter ----------------
__global__ __launch_bounds__(256) void k2_select(
    const uint2* __restrict__ pairs, const unsigned* __restrict__ suff,
    float* __restrict__ out)
{
    __shared__ unsigned keyA[8192];     // 32 KB
    __shared__ unsigned colA[8192];     // 32 KB
    __shared__ unsigned hist[4096];     // 16 KB
    __shared__ unsigned rs[256];
    __shared__ unsigned LsS[8];
    __shared__ unsigned wp[4];
    __shared__ unsigned shb0, sh_d, sh_need, sh_tcnt;
    __shared__ unsigned tlist[256];

    const int tid  = threadIdx.x;
    const int wave = tid >> 6;
    const int lane = tid & 63;
    const int r    = blockIdx.x;

    // row suffix counts per byte + zero hist
    {
        unsigned v = 0;
#pragma unroll
        for (int sg = 0; sg < 8; ++sg) v += suff[(r * 8 + sg) * 256 + tid];
        rs[tid] = v;
    }
    for (int i = tid; i < 4096; i += 256) hist[i] = 0u;
    __syncthreads();                                     // B1
    if (rs[tid] >= KSEL && (tid == 255 || rs[tid + 1] < KSEL)) shb0 = (unsigned)tid;
    __syncthreads();                                     // B2
    const unsigned b0    = shb0;
    const unsigned above = (b0 < 255u) ? rs[b0 + 1] : 0u;  // byte > b0, all selected
    const unsigned need2 = KSEL - above;                   // quota in b0-class

    if (tid < 8) LsS[tid] = suff[(r * 8 + tid) * 256 + b0];
    __syncthreads();                                     // B3

    unsigned ls[8], off[9];
    off[0] = 0;
#pragma unroll
    for (int sg = 0; sg < 8; ++sg) { ls[sg] = LsS[sg]; off[sg + 1] = off[sg] + ls[sg]; }
    const unsigned total = off[8];

    // gather candidate prefixes (byte >= b0)
#pragma unroll
    for (int sg = 0; sg < 8; ++sg) {
        const uint2* pp = pairs + (size_t)(r * 8 + sg) * 1024;
        for (unsigned i = tid; i < ls[sg]; i += 256) {
            uint2 e = pp[i];
            keyA[off[sg] + i] = e.x;
            colA[off[sg] + i] = e.y + (unsigned)(sg * 1024);
        }
    }
    __syncthreads();                                     // B4

    // ---- refine L1: bits [23:12] of b0-class ----
    for (unsigned i = tid; i < total; i += 256) {
        const unsigned k = keyA[i];
        if ((k >> 24) == b0) atomicAdd(&hist[(k >> 12) & 4095u], 1u);
    }
    __syncthreads();                                     // B5
    {
        unsigned cc[16], tot = 0;
        const int tb = 4095 - 16 * tid;
#pragma unroll
        for (int j = 0; j < 16; ++j) { cc[j] = hist[tb - j]; tot += cc[j]; }
        unsigned s2 = tot;
#pragma unroll
        for (int o = 1; o < 64; o <<= 1) {
            unsigned nv = __shfl_up(s2, o, 64);
            if (lane >= o) s2 += nv;
        }
        if (lane == 63) wp[wave] = s2;
        __syncthreads();                                 // B6
        unsigned add = 0;
        for (int w = 0; w < wave; ++w) add += wp[w];
        unsigned cum = s2 + add - tot;                   // count in higher bins
#pragma unroll
        for (int j = 0; j < 16; ++j) {
            const unsigned nc = cum + cc[j];
            if (nc >= need2 && cum < need2) { sh_d = (unsigned)(tb - j); sh_need = need2 - cum; }
            cum = nc;
        }
    }
    __syncthreads();                                     // B7
    const unsigned p1 = sh_d;
    const unsigned needA = sh_need;
    for (int i = tid; i < 4096; i += 256) hist[i] = 0u;
    __syncthreads();                                     // B8

    // ---- refine L2: bits [11:0] among b0-class with mid bits == p1 ----
    for (unsigned i = tid; i < total; i += 256) {
        const unsigned k = keyA[i];
        if ((k >> 24) == b0 && ((k >> 12) & 4095u) == p1)
            atomicAdd(&hist[k & 4095u], 1u);
    }
    __syncthreads();                                     // B9
    {
        unsigned cc[16], tot = 0;
        const int tb = 4095 - 16 * tid;
#pragma unroll
        for (int j = 0; j < 16; ++j) { cc[j] = hist[tb - j]; tot += cc[j]; }
        unsigned s2 = tot;
#pragma unroll
        for (int o = 1; o < 64; o <<= 1) {
            unsigned nv = __shfl_up(s2, o, 64);
            if (lane >= o) s2 += nv;
        }
        if (lane == 63) wp[wave] = s2;
        __syncthreads();                                 // B10
        unsigned add = 0;
        for (int w = 0; w < wave; ++w) add += wp[w];
        unsigned cum = s2 + add - tot;
#pragma unroll
        for (int j = 0; j < 16; ++j) {
            const unsigned nc = cum + cc[j];
            if (nc >= needA && cum < needA) { sh_d = (unsigned)(tb - j); sh_need = needA - cum; }
            cum = nc;
        }
    }
    __syncthreads();                                     // B11
    const unsigned Tlow  = (p1 << 12) | sh_d;            // low-24 threshold
    const unsigned needF = sh_need;                      // ties kept (lowest col)
    const unsigned T     = (b0 << 24) | Tlow;
    if (tid == 0) sh_tcnt = 0u;
    __syncthreads();                                     // B12

    // ---- collect tied columns (typically 1) ----
    for (unsigned i = tid; i < total; i += 256) {
        if (keyA[i] == T) {
            const unsigned idx = atomicAdd(&sh_tcnt, 1u);
            if (idx < 256u) tlist[idx] = colA[i];
        }
    }
    __syncthreads();                                     // B13
    const unsigned L = sh_tcnt;

    // ---- emit: +1.0 at selected columns (out already == mem) ----
    for (unsigned i = tid; i < total; i += 256) {
        const unsigned k   = keyA[i];
        const unsigned col = colA[i];
        bool sel;
        if ((k >> 24) > b0) {
            sel = true;
        } else {                                  // byte == b0 by construction
            const unsigned low = k & 0xFFFFFFu;
            if (low > Tlow)      sel = true;
            else if (low < Tlow) sel = false;
            else {
                unsigned rk = 0;
                if (L <= 256u) {
                    for (unsigned q = 0; q < L; ++q) rk += (tlist[q] < col) ? 1u : 0u;
                } else {          // pathological mass-tie fallback (never on real data)
                    for (unsigned q = 0; q < total; ++q)
                        rk += (keyA[q] == T && colA[q] < col) ? 1u : 0u;
                }
                sel = (rk < needF);
            }
        }
        if (sel) atomicAdd(out + r * NCOL + col, 1.0f);
    }
}

// ---------------- Fallback: proven R5 single kernel (~64 us) ----------------
#define H0S 4097
__global__ __launch_bounds__(1024) void topk_single32(
    const float* __restrict__ logits, const float* __restrict__ noise,
    const float* __restrict__ mem, float* __restrict__ out)
{
    __shared__ unsigned hist0[4 * H0S];
    __shared__ __align__(16) unsigned hist1[4096];
    __shared__ unsigned hist2[256];
    __shared__ unsigned wpart[16];
    __shared__ unsigned sh_pn[2];

    const int tid  = threadIdx.x;
    const int wave = tid >> 6;
    const int lane = tid & 63;
    const int grp  = wave >> 2;
    const int base = blockIdx.x * NCOL + tid * 8;

    float4 lg0 = ((const float4*)(logits + base))[0];
    float4 lg1 = ((const float4*)(logits + base))[1];
    float4 no0 = ((const float4*)(noise  + base))[0];
    float4 no1 = ((const float4*)(noise  + base))[1];
    float4 mm0 = ((const float4*)(mem    + base))[0];
    float4 mm1 = ((const float4*)(mem    + base))[1];

    unsigned key[8];
    key[0] = float_to_key(lg0.x + no0.x + mm0.x * -1000.0f);
    key[1] = float_to_key(lg0.y + no0.y + mm0.y * -1000.0f);
    key[2] = float_to_key(lg0.z + no0.z + mm0.z * -1000.0f);
    key[3] = float_to_key(lg0.w + no0.w + mm0.w * -1000.0f);
    key[4] = float_to_key(lg1.x + no1.x + mm1.x * -1000.0f);
    key[5] = float_to_key(lg1.y + no1.y + mm1.y * -1000.0f);
    key[6] = float_to_key(lg1.z + no1.z + mm1.z * -1000.0f);
    key[7] = float_to_key(lg1.w + no1.w + mm1.w * -1000.0f);

    for (int i = tid; i < 4 * H0S; i += 1024) hist0[i] = 0u;
    for (int i = tid; i < 4096; i += 1024) hist1[i] = 0u;
    if (tid < 256) hist2[tid] = 0u;
    __syncthreads();

    {
        unsigned* h0 = hist0 + grp * H0S;
#pragma unroll
        for (int i = 0; i < 8; ++i) atomicAdd(&h0[key[i] >> 20], 1u);
    }
    __syncthreads();

    unsigned need = KSEL;
    unsigned p12, p24;
    const int dbase = 4095 - 4 * tid;
    {
        unsigned c[4], tot = 0;
#pragma unroll
        for (int j = 0; j < 4; ++j) {
            const int d = dbase - j;
            c[j] = hist0[d] + hist0[H0S + d] + hist0[2 * H0S + d] + hist0[3 * H0S + d];
            tot += c[j];
        }
        unsigned s = tot;
#pragma unroll
        for (int off = 1; off < 64; off <<= 1) {
            unsigned nv = __shfl_up(s, off, 64);
            if (lane >= off) s += nv;
        }
        if (lane == 63) wpart[wave] = s;
        __syncthreads();
        unsigned add = 0;
        for (int w = 0; w < wave; ++w) add += wpart[w];
        unsigned cum = s + add - tot;
#pragma unroll
        for (int j = 0; j < 4; ++j) {
            unsigned nc = cum + c[j];
            if (nc >= need && cum < need) { sh_pn[0] = (unsigned)(dbase - j); sh_pn[1] = need - cum; }
            cum = nc;
        }
    }
    __syncthreads();
    p12 = sh_pn[0]; need = sh_pn[1];

#pragma unroll
    for (int i = 0; i < 8; ++i)
        if ((key[i] >> 20) == p12)
            atomicAdd(&hist1[(key[i] >> 8) & 4095u], 1u);
    __syncthreads();
    {
        uint4 v = *(const uint4*)&hist1[dbase - 3];
        unsigned c[4] = {v.w, v.z, v.y, v.x};
        unsigned tot = c[0] + c[1] + c[2] + c[3];
        unsigned s = tot;
#pragma unroll
        for (int off = 1; off < 64; off <<= 1) {
            unsigned nv = __shfl_up(s, off, 64);
            if (lane >= off) s += nv;
        }
        if (lane == 63) wpart[wave] = s;
        __syncthreads();
        unsigned add = 0;
        for (int w = 0; w < wave; ++w) add += wpart[w];
        unsigned cum = s + add - tot;
#pragma unroll
        for (int j = 0; j < 4; ++j) {
            unsigned nc = cum + c[j];
            if (nc >= need && cum < need) { sh_pn[0] = (unsigned)(dbase - j); sh_pn[1] = need - cum; }
            cum = nc;
        }
    }
    __syncthreads();
    p24 = (p12 << 12) | sh_pn[0]; need = sh_pn[1];

#pragma unroll
    for (int i = 0; i < 8; ++i)
        if ((key[i] >> 8) == p24)
            atomicAdd(&hist2[key[i] & 255u], 1u);
    __syncthreads();

    if (wave == 0) {
        const int d0 = 255 - 4 * lane;
        unsigned c0 = hist2[d0], c1 = hist2[d0 - 1],
                 c2 = hist2[d0 - 2], c3 = hist2[d0 - 3];
        unsigned tot = c0 + c1 + c2 + c3, s = tot;
#pragma unroll
        for (int off = 1; off < 64; off <<= 1) {
            unsigned nv = __shfl_up(s, off, 64);
            if (lane >= off) s += nv;
        }
        unsigned P = s - tot;
        unsigned cum0 = P + c0, cum1 = cum0 + c1, cum2 = cum1 + c2, cum3 = cum2 + c3;
        if (cum0 >= need && P < need)         { sh_pn[0] = (unsigned)d0;       sh_pn[1] = need - P;    }
        else if (cum1 >= need && cum0 < need) { sh_pn[0] = (unsigned)(d0 - 1); sh_pn[1] = need - cum0; }
        else if (cum2 >= need && cum1 < need) { sh_pn[0] = (unsigned)(d0 - 2); sh_pn[1] = need - cum1; }
        else if (cum3 >= need && cum2 < need) { sh_pn[0] = (unsigned)(d0 - 3); sh_pn[1] = need - cum2; }
    }
    __syncthreads();
    const unsigned T     = (p24 << 8) | sh_pn[0];
    const unsigned needF = sh_pn[1];

    unsigned local_eq = 0;
#pragma unroll
    for (int i = 0; i < 8; ++i) local_eq += (key[i] == T) ? 1u : 0u;
    unsigned s2 = local_eq;
#pragma unroll
    for (int off = 1; off < 64; off <<= 1) {
        unsigned nv = __shfl_up(s2, off, 64);
        if (lane >= off) s2 += nv;
    }
    if (lane == 63) wpart[wave] = s2;
    __syncthreads();
    unsigned rank = s2 - local_eq;
    for (int w = 0; w < wave; ++w) rank += wpart[w];

    float o[8];
#pragma unroll
    for (int i = 0; i < 8; ++i) {
        float sel;
        if (key[i] > T)       sel = 1.0f;
        else if (key[i] == T) { sel = (rank < needF) ? 1.0f : 0.0f; ++rank; }
        else                  sel = 0.0f;
        o[i] = sel;
    }
    o[0] += mm0.x; o[1] += mm0.y; o[2] += mm0.z; o[3] += mm0.w;
    o[4] += mm1.x; o[5] += mm1.y; o[6] += mm1.z; o[7] += mm1.w;
    ((float4*)(out + base))[0] = make_float4(o[0], o[1], o[2], o[3]);
    ((float4*)(out + base))[1] = make_float4(o[4], o[5], o[6], o[7]);
}

extern "C" void kernel_launch(void* const* d_in, const int* in_sizes, int n_in,
                              void* d_out, int out_size, void* d_ws, size_t ws_size,
                              hipStream_t stream) {
    const float* logits = (const float*)d_in[0];
    const float* noise  = (const float*)d_in[1];
    const float* mem    = (const float*)d_in[2];
    float* out = (float*)d_out;

    const size_t pairs_bytes = (size_t)256 * 1024 * sizeof(uint2);   // 2 MB
    const size_t suff_bytes  = (size_t)256 * 256 * sizeof(unsigned); // 256 KB

    if (ws_size >= pairs_bytes + suff_bytes) {
        uint2*    pairs = (uint2*)d_ws;
        unsigned* suff  = (unsigned*)((char*)d_ws + pairs_bytes);
        k1_sort<<<256, 256, 0, stream>>>(logits, noise, mem, out, pairs, suff);
        k2_select<<<NROW, 256, 0, stream>>>(pairs, suff, out);
    } else {
        topk_single32<<<NROW, 1024, 0, stream>>>(logits, noise, mem, out);
    }
}